// Round 5
// baseline (195.639 us; speedup 1.0000x reference)
//
#include <hip/hip_runtime.h>
#include <hip/hip_bf16.h>
#include <math.h>

#define B_ 32
#define N_ 4096
#define C_ 64
#define H_ 256
#define P_ 8
#define NPOOL 1024

typedef short bf16x8 __attribute__((ext_vector_type(8)));
typedef float f32x4 __attribute__((ext_vector_type(4)));

union BF8 { bf16x8 v; unsigned int w[4]; };

__device__ __forceinline__ unsigned short f2bf(float f) {
    union { float f; unsigned int u; } v; v.f = f;
    unsigned int r = v.u + 0x7FFFu + ((v.u >> 16) & 1u);
    return (unsigned short)(r >> 16);
}
__device__ __forceinline__ float bf2f(unsigned short h) {
    union { float f; unsigned int u; } v; v.u = ((unsigned int)h) << 16; return v.f;
}
__device__ __forceinline__ unsigned int pk_bf16(float lo, float hi) {
    unsigned int r;
    asm("v_cvt_pk_bf16_f32 %0, %1, %2" : "=v"(r) : "v"(lo), "v"(hi));
    return r;
}
// wk * gelu_tanh(x);  gelu = x*(1-rc), rc = 1/(exp2(y2)+1), y2 = 2*log2e*0.7978845608*(x+0.044715x^3)
__device__ __forceinline__ float gelu_w(float x, float wk) {
    float x2 = x * x;
    float y2 = x * fmaf(0.10294322f, x2, 2.30220772f);
    float e  = __builtin_amdgcn_exp2f(y2);
    float rc = __builtin_amdgcn_rcpf(e + 1.0f);
    float wx = wk * x;
    return fmaf(-wx, rc, wx);
}

// h-permutation: h = 32*(t>>1) + 8*(d>>2) + 4*(t&1) + (d&3)
// inverse: t = ((h>>5)<<1)|((h>>2)&1); d = (((h>>3)&3)<<2)|(h&3)

// ---------------- prep (W1P permuted, W2T, b1P) + pool + last-block router ----------------
// blocks 0..511:    W1P[e][t*16+d][c] = bf16(W1[e][c][hperm(t,d)])   (reads coalesced)
// blocks 512..1023: W2T[e][c][h]      = bf16(W2[e][h][c])            (reads coalesced)
// blocks 1024..1031: b1P[e][t*16+d]   = bf16(b1[e][hperm(t,d)])
// blocks 1032..2055: pool partial sums (atomic) + last block computes router
__global__ void prep_pool(const float* __restrict__ W1, const float* __restrict__ W2,
                          const float* __restrict__ b1, const float* __restrict__ u,
                          const float* __restrict__ Wr, const float* __restrict__ br,
                          unsigned short* __restrict__ W1P, unsigned short* __restrict__ W2T,
                          unsigned short* __restrict__ b1P, float* __restrict__ pooled,
                          int* __restrict__ counter, float4* __restrict__ route) {
    int bid = blockIdx.x, tid = threadIdx.x;
    if (bid < 512) {
        int idx = bid * 256 + tid;              // (e,c,h) input order -> coalesced read
        int e = idx >> 14, h = idx & 255, c = (idx >> 8) & 63;
        int t = ((h >> 5) << 1) | ((h >> 2) & 1);
        int d = (((h >> 3) & 3) << 2) | (h & 3);
        W1P[(e << 14) + (((t << 4) | d) << 6) + c] = f2bf(W1[idx]);
        return;
    }
    if (bid < 1024) {
        int idx = (bid - 512) * 256 + tid;      // (e,h,c) input order -> coalesced read
        int e = idx >> 14, c = idx & 63, h = (idx >> 6) & 255;
        W2T[(e << 14) + (c << 8) + h] = f2bf(W2[idx]);
        return;
    }
    if (bid < 1032) {
        int oi = (bid - 1024) * 256 + tid;      // (e,h)
        int e = oi >> 8, h = oi & 255;
        int t = ((h >> 5) << 1) | ((h >> 2) & 1);
        int d = (((h >> 3) & 3) << 2) | (h & 3);
        b1P[(e << 8) + (t << 4) + d] = f2bf(b1[oi]);
        return;
    }
    // ---- pool ----
    int pb = bid - 1032;
    int b = pb >> 5, chunk = pb & 31;
    int c = tid & 63, rg = tid >> 6;
    const float* base = u + ((size_t)b * N_ + (size_t)chunk * 128) * C_;
    float s = 0.f;
    #pragma unroll 4
    for (int i = 0; i < 32; ++i) s += base[(i * 4 + rg) * C_ + c];
    __shared__ float red[4][64];
    __shared__ int isLast;
    __shared__ float lgAll[B_][P_];
    red[rg][c] = s;
    __syncthreads();
    if (tid < 64) {
        float t4 = red[0][tid] + red[1][tid] + red[2][tid] + red[3][tid];
        atomicAdd(&pooled[b * C_ + tid], t4);
        __threadfence();
    }
    __syncthreads();
    if (tid == 0) {
        int old = atomicAdd(counter, 1);
        isLast = (old == NPOOL - 1);
    }
    __syncthreads();
    if (!isLast) return;
    __threadfence();
    // ---- router (one block, 256 threads = 32 b x 8 p) ----
    {
        int rb = tid >> 3, p = tid & 7;
        const float* pb2 = pooled + rb * C_;
        float sacc = br[p];
        #pragma unroll
        for (int cc = 0; cc < C_; ++cc) {
            float pv = __hip_atomic_load(&pb2[cc], __ATOMIC_RELAXED, __HIP_MEMORY_SCOPE_AGENT);
            sacc += pv * (1.0f / N_) * Wr[cc * P_ + p];
        }
        lgAll[rb][p] = sacc;
    }
    __syncthreads();
    if (tid < B_) {
        float lg[P_];
        #pragma unroll
        for (int p = 0; p < P_; ++p) lg[p] = lgAll[tid][p];
        int i0 = 0;
        #pragma unroll
        for (int p = 1; p < P_; ++p) if (lg[p] > lg[i0]) i0 = p;   // strict >: lowest idx on tie
        int i1 = (i0 == 0) ? 1 : 0;
        #pragma unroll
        for (int p = 0; p < P_; ++p) if (p != i0 && lg[p] > lg[i1]) i1 = p;
        float e1 = __expf(lg[i1] - lg[i0]);
        float w0 = 1.f / (1.f + e1);
        route[tid] = make_float4(w0, e1 * w0, __int_as_float(i0), __int_as_float(i1));
    }
}

// ---------------- main MoE-MLP: no LDS, no barriers, independent waves ----------------
// grid 1024 blocks x 256 thr; each wave owns 32 n-rows of one sample b.
// 4 blocks/CU resident (4 waves/SIMD) for latency hiding.
// GEMM1 (swapped, h-permuted W1P) leaves h1 exactly in GEMM2's A-fragment layout.
__global__ __launch_bounds__(256, 4)
void moe_main(const float* __restrict__ u, const unsigned short* __restrict__ W1P,
              const unsigned short* __restrict__ W2T, const unsigned short* __restrict__ b1P,
              const float* __restrict__ b2, const float4* __restrict__ route,
              float* __restrict__ out) {
    const int tid = threadIdx.x;
    const int wv = tid >> 6, lane = tid & 63;
    const int r = lane & 15, g = lane >> 4;
    const int b = blockIdx.x >> 5;
    const int nslab = ((blockIdx.x & 31) << 2) + wv;
    const int n0 = nslab << 5;                       // 32 rows per wave

    float4 rd = route[b];
    const float wk2[2] = { rd.x, rd.y };
    const int eidx[2] = { __float_as_int(rd.z), __float_as_int(rd.w) };

    // ---- u B-fragments: ub[rt][ks] = u[n0+rt*16+r][ks*32+g*8 .. +8] as bf16x8
    const float* ubase = u + ((size_t)b * N_ + n0) * C_;
    bf16x8 ub[2][2];
    #pragma unroll
    for (int rt = 0; rt < 2; ++rt) {
        const float* rp = ubase + (rt * 16 + r) * C_;
        #pragma unroll
        for (int ks = 0; ks < 2; ++ks) {
            float4 lo = *(const float4*)(rp + ks * 32 + g * 8);
            float4 hi = *(const float4*)(rp + ks * 32 + g * 8 + 4);
            BF8 t;
            t.w[0] = pk_bf16(lo.x, lo.y); t.w[1] = pk_bf16(lo.z, lo.w);
            t.w[2] = pk_bf16(hi.x, hi.y); t.w[3] = pk_bf16(hi.z, hi.w);
            ub[rt][ks] = t.v;
        }
    }

    f32x4 acc2[4][2];                                // [ct][rt], spans both experts (wk folded in)
    #pragma unroll
    for (int ct = 0; ct < 4; ++ct)
        #pragma unroll
        for (int rt = 0; rt < 2; ++rt)
            #pragma unroll
            for (int q = 0; q < 4; ++q) acc2[ct][rt][q] = 0.f;

    for (int ke = 0; ke < 2; ++ke) {
        const int e = eidx[ke];
        const float wk = wk2[ke];
        const unsigned short* w1p = W1P + (e << 14);
        const unsigned short* w2t = W2T + (e << 14);
        const unsigned short* b1e = b1P + (e << 8);

        #pragma unroll
        for (int tp = 0; tp < 8; ++tp) {             // t-pair == kk of GEMM2
            // GEMM1: A = W1P rows (permuted h), B = u^T
            bf16x8 a1[2][2];
            #pragma unroll
            for (int tt = 0; tt < 2; ++tt)
                #pragma unroll
                for (int ks = 0; ks < 2; ++ks)
                    a1[tt][ks] = *(const bf16x8*)(w1p + ((tp * 32 + tt * 16 + r) << 6) + ks * 32 + g * 8);
            // GEMM2 B-fragments issued early: latency hides under GEMM1+gelu
            bf16x8 b2f[4];
            #pragma unroll
            for (int ct = 0; ct < 4; ++ct)
                b2f[ct] = *(const bf16x8*)(w2t + ((ct * 16 + r) << 8) + tp * 32 + g * 8);

            f32x4 acc1[2][2];
            #pragma unroll
            for (int tt = 0; tt < 2; ++tt)
                #pragma unroll
                for (int rt = 0; rt < 2; ++rt)
                    #pragma unroll
                    for (int q = 0; q < 4; ++q) acc1[tt][rt][q] = 0.f;
            #pragma unroll
            for (int ks = 0; ks < 2; ++ks)
                #pragma unroll
                for (int tt = 0; tt < 2; ++tt)
                    #pragma unroll
                    for (int rt = 0; rt < 2; ++rt)
                        acc1[tt][rt] = __builtin_amdgcn_mfma_f32_16x16x32_bf16(
                            a1[tt][ks], ub[rt][ks], acc1[tt][rt], 0, 0, 0);

            // bias + wk*gelu + pack -> GEMM2 A-fragments (no shuffle needed, by h-permutation)
            float bv[8];   // b1P[e][tp*32 + tt*16 + 4g + j]
            {
                const unsigned short* bp = b1e + tp * 32 + 4 * g;
                #pragma unroll
                for (int j = 0; j < 4; ++j) { bv[j] = bf2f(bp[j]); bv[4 + j] = bf2f(bp[16 + j]); }
            }
            bf16x8 a2[2];
            #pragma unroll
            for (int rt = 0; rt < 2; ++rt) {
                float gv[8];
                #pragma unroll
                for (int j = 0; j < 4; ++j) {
                    gv[j]     = gelu_w(acc1[0][rt][j] + bv[j],     wk);
                    gv[4 + j] = gelu_w(acc1[1][rt][j] + bv[4 + j], wk);
                }
                BF8 t;
                t.w[0] = pk_bf16(gv[0], gv[1]); t.w[1] = pk_bf16(gv[2], gv[3]);
                t.w[2] = pk_bf16(gv[4], gv[5]); t.w[3] = pk_bf16(gv[6], gv[7]);
                a2[rt] = t.v;
            }

            // GEMM2: contract k = h in [tp*32, tp*32+32)
            #pragma unroll
            for (int ct = 0; ct < 4; ++ct)
                #pragma unroll
                for (int rt = 0; rt < 2; ++rt)
                    acc2[ct][rt] = __builtin_amdgcn_mfma_f32_16x16x32_bf16(
                        a2[rt], b2f[ct], acc2[ct][rt], 0, 0, 0);
        }
    }

    // ---- epilogue: out = u + acc2 + sum_e wk_e*b2_e   (residual re-read: L1/L2-hot)
    float bsum[4];
    #pragma unroll
    for (int ct = 0; ct < 4; ++ct) {
        int c = ct * 16 + r;
        bsum[ct] = wk2[0] * b2[eidx[0] * C_ + c] + wk2[1] * b2[eidx[1] * C_ + c];
    }
    float* obase = out + ((size_t)b * N_ + n0) * C_;
    #pragma unroll
    for (int rt = 0; rt < 2; ++rt)
        #pragma unroll
        for (int j = 0; j < 4; ++j) {
            int row = rt * 16 + 4 * g + j;
            #pragma unroll
            for (int ct = 0; ct < 4; ++ct) {
                int c = ct * 16 + r;
                obase[row * C_ + c] = ubase[row * C_ + c] + acc2[ct][rt][j] + bsum[ct];
            }
        }
}

extern "C" void kernel_launch(void* const* d_in, const int* in_sizes, int n_in,
                              void* d_out, int out_size, void* d_ws, size_t ws_size,
                              hipStream_t stream) {
    const float* u  = (const float*)d_in[0];
    const float* W1 = (const float*)d_in[1];
    const float* b1 = (const float*)d_in[2];
    const float* W2 = (const float*)d_in[3];
    const float* b2 = (const float*)d_in[4];
    const float* Wr = (const float*)d_in[5];
    const float* br = (const float*)d_in[6];
    float* out = (float*)d_out;

    char* ws = (char*)d_ws;
    float* pooled        = (float*)ws;                         // 8192 B
    int* counter         = (int*)(ws + 8192);                  // 64 B slot
    float4* route        = (float4*)(ws + 8256);               // 512 B
    unsigned short* b1P  = (unsigned short*)(ws + 8768);       // 4096 B
    unsigned short* W1P  = (unsigned short*)(ws + 16384);      // 256 KB
    unsigned short* W2T  = (unsigned short*)(ws + 16384 + 262144); // 256 KB  (end = 540672)

    hipMemsetAsync(ws, 0, 8256, stream);   // pooled + counter
    prep_pool<<<2056, 256, 0, stream>>>(W1, W2, b1, u, Wr, br, W1P, W2T, b1P, pooled, counter, route);
    moe_main<<<1024, 256, 0, stream>>>(u, W1P, W2T, b1P, b2, route, out);
}

// Round 6
// 171.297 us; speedup vs baseline: 1.1421x; 1.1421x over previous
//
#include <hip/hip_runtime.h>
#include <hip/hip_bf16.h>
#include <math.h>

#define B_ 32
#define N_ 4096
#define C_ 64
#define H_ 256
#define P_ 8
#define NPOOL 1024

typedef short bf16x8 __attribute__((ext_vector_type(8)));
typedef float f32x4 __attribute__((ext_vector_type(4)));

union BF8 { bf16x8 v; unsigned int w[4]; };

__device__ __forceinline__ unsigned short f2bf(float f) {
    union { float f; unsigned int u; } v; v.f = f;
    unsigned int r = v.u + 0x7FFFu + ((v.u >> 16) & 1u);
    return (unsigned short)(r >> 16);
}
__device__ __forceinline__ float bf2f(unsigned short h) {
    union { float f; unsigned int u; } v; v.u = ((unsigned int)h) << 16; return v.f;
}
__device__ __forceinline__ unsigned int pk_bf16(float lo, float hi) {
    unsigned int r;
    asm("v_cvt_pk_bf16_f32 %0, %1, %2" : "=v"(r) : "v"(lo), "v"(hi));
    return r;
}
// wk * gelu_tanh(x)
__device__ __forceinline__ float gelu_w(float x, float wk) {
    float x2 = x * x;
    float y2 = x * fmaf(0.10294322f, x2, 2.30220772f);
    float e  = __builtin_amdgcn_exp2f(y2);
    float rc = __builtin_amdgcn_rcpf(e + 1.0f);
    float wx = wk * x;
    return fmaf(-wx, rc, wx);
}
// h-permutation: h = 32*(t>>1) + 8*(d>>2) + 4*(t&1) + (d&3), p = t*16+d
__device__ __forceinline__ int hperm_p(int p) {
    int t = p >> 4, d = p & 15;
    return ((t >> 1) << 5) + ((d >> 2) << 3) + ((t & 1) << 2) + (d & 3);
}

// ---------------- prep (LDS-staged transposes) + pool + last-block router ----------------
// blocks 0..15:  (e = bid>>1, m = bid&1) m0: W1P[e][p][c] = bf16(W1[e][c][hperm(p)])
//                                         m1: W2T[e][c][h] = bf16(W2[e][h][c])
// block 16:      b1P[e][p] = bf16(b1[e][hperm(p)])
// blocks 17..1040: pool partial sums (atomic) + last block computes router
__global__ void prep_pool(const float* __restrict__ W1, const float* __restrict__ W2,
                          const float* __restrict__ b1, const float* __restrict__ u,
                          const float* __restrict__ Wr, const float* __restrict__ br,
                          unsigned short* __restrict__ W1P, unsigned short* __restrict__ W2T,
                          unsigned short* __restrict__ b1P, float* __restrict__ pooled,
                          int* __restrict__ counter, float4* __restrict__ route) {
    __shared__ union {
        unsigned short t[256 * 66];                  // W1 stage [h][c], stride 66
        unsigned short s[64 * 258];                  // W2 stage [c][h], stride 258
        struct { float red[4][64]; float lgAll[B_][P_]; } pr;
    } sh;
    __shared__ int isLast;

    const int bid = blockIdx.x, tid = threadIdx.x;

    if (bid < 16) {
        const int e = bid >> 1, m = bid & 1;
        if (m == 0) {
            // ---- W1 transpose+perm: in [c][h] (64x256 f32) -> out [p][c] (256x64 bf16)
            const float* src = W1 + (e << 14);
            #pragma unroll
            for (int i = 0; i < 16; ++i) {
                int c = i * 4 + (tid >> 6), h4 = (tid & 63) * 4;
                float4 v = *(const float4*)(src + c * 256 + h4);
                sh.t[(h4 + 0) * 66 + c] = f2bf(v.x);
                sh.t[(h4 + 1) * 66 + c] = f2bf(v.y);
                sh.t[(h4 + 2) * 66 + c] = f2bf(v.z);
                sh.t[(h4 + 3) * 66 + c] = f2bf(v.w);
            }
            __syncthreads();
            unsigned short* dst = W1P + (e << 14);
            #pragma unroll
            for (int i = 0; i < 32; ++i) {
                int p = i * 8 + (tid >> 5), c2 = (tid & 31) * 2;
                int h = hperm_p(p);
                *(ushort2*)(dst + (p << 6) + c2) = *(const ushort2*)&sh.t[h * 66 + c2];
            }
        } else {
            // ---- W2 transpose: in [h][c] (256x64 f32) -> out [c][h] (64x256 bf16)
            const float* src = W2 + (e << 14);
            #pragma unroll
            for (int i = 0; i < 16; ++i) {
                int h = i * 16 + (tid >> 4), c4 = (tid & 15) * 4;
                float4 v = *(const float4*)(src + (h << 6) + c4);
                sh.s[(c4 + 0) * 258 + h] = f2bf(v.x);
                sh.s[(c4 + 1) * 258 + h] = f2bf(v.y);
                sh.s[(c4 + 2) * 258 + h] = f2bf(v.z);
                sh.s[(c4 + 3) * 258 + h] = f2bf(v.w);
            }
            __syncthreads();
            unsigned short* dst = W2T + (e << 14);
            #pragma unroll
            for (int i = 0; i < 32; ++i) {
                int c = i * 2 + (tid >> 7), h2 = (tid & 127) * 2;
                *(ushort2*)(dst + (c << 8) + h2) = *(const ushort2*)&sh.s[c * 258 + h2];
            }
        }
        return;
    }
    if (bid == 16) {
        #pragma unroll
        for (int i = 0; i < 8; ++i) {
            int oi = i * 256 + tid;                  // (e,p)
            int e = oi >> 8, p = oi & 255;
            b1P[oi] = f2bf(b1[(e << 8) + hperm_p(p)]);
        }
        return;
    }
    // ---- pool ----
    int pb = bid - 17;
    int b = pb >> 5, chunk = pb & 31;
    int c = tid & 63, rg = tid >> 6;
    const float* base = u + ((size_t)b * N_ + (size_t)chunk * 128) * C_;
    float s = 0.f;
    #pragma unroll 4
    for (int i = 0; i < 32; ++i) s += base[(i * 4 + rg) * C_ + c];
    sh.pr.red[rg][c] = s;
    __syncthreads();
    if (tid < 64) {
        float t4 = sh.pr.red[0][tid] + sh.pr.red[1][tid] + sh.pr.red[2][tid] + sh.pr.red[3][tid];
        atomicAdd(&pooled[b * C_ + tid], t4);
        __threadfence();
    }
    __syncthreads();
    if (tid == 0) {
        int old = atomicAdd(counter, 1);
        isLast = (old == NPOOL - 1);
    }
    __syncthreads();
    if (!isLast) return;
    __threadfence();
    // ---- router (256 threads = 32 b x 8 p) ----
    {
        int rb = tid >> 3, p = tid & 7;
        const float* pb2 = pooled + rb * C_;
        float sacc = br[p];
        #pragma unroll
        for (int cc = 0; cc < C_; ++cc) {
            float pv = __hip_atomic_load(&pb2[cc], __ATOMIC_RELAXED, __HIP_MEMORY_SCOPE_AGENT);
            sacc += pv * (1.0f / N_) * Wr[cc * P_ + p];
        }
        sh.pr.lgAll[rb][p] = sacc;
    }
    __syncthreads();
    if (tid < B_) {
        float lg[P_];
        #pragma unroll
        for (int p = 0; p < P_; ++p) lg[p] = sh.pr.lgAll[tid][p];
        int i0 = 0;
        #pragma unroll
        for (int p = 1; p < P_; ++p) if (lg[p] > lg[i0]) i0 = p;   // strict >: lowest idx on tie
        int i1 = (i0 == 0) ? 1 : 0;
        #pragma unroll
        for (int p = 0; p < P_; ++p) if (p != i0 && lg[p] > lg[i1]) i1 = p;
        float e1 = __expf(lg[i1] - lg[i0]);
        float w0 = 1.f / (1.f + e1);
        route[tid] = make_float4(w0, e1 * w0, __int_as_float(i0), __int_as_float(i1));
    }
}

// one tp-step: GEMM1 (2 h-tiles x 4 n-tiles) -> bias+wk*gelu -> pack -> GEMM2
__device__ __forceinline__ void comp_tp(const bf16x8 (&A)[2][2], const bf16x8 (&Bw)[4],
                                        ushort4 bva, ushort4 bvb, float wk,
                                        const bf16x8 (&ub)[4][2], f32x4 (&acc2)[4][4]) {
    f32x4 c1[2][4];
    #pragma unroll
    for (int tt = 0; tt < 2; ++tt)
        #pragma unroll
        for (int rt = 0; rt < 4; ++rt)
            #pragma unroll
            for (int q = 0; q < 4; ++q) c1[tt][rt][q] = 0.f;
    #pragma unroll
    for (int ks = 0; ks < 2; ++ks)
        #pragma unroll
        for (int tt = 0; tt < 2; ++tt)
            #pragma unroll
            for (int rt = 0; rt < 4; ++rt)
                c1[tt][rt] = __builtin_amdgcn_mfma_f32_16x16x32_bf16(A[tt][ks], ub[rt][ks], c1[tt][rt], 0, 0, 0);
    float bv[8];
    bv[0] = bf2f(bva.x); bv[1] = bf2f(bva.y); bv[2] = bf2f(bva.z); bv[3] = bf2f(bva.w);
    bv[4] = bf2f(bvb.x); bv[5] = bf2f(bvb.y); bv[6] = bf2f(bvb.z); bv[7] = bf2f(bvb.w);
    #pragma unroll
    for (int rt = 0; rt < 4; ++rt) {
        float gv[8];
        #pragma unroll
        for (int j = 0; j < 4; ++j) {
            gv[j]     = gelu_w(c1[0][rt][j] + bv[j],     wk);
            gv[4 + j] = gelu_w(c1[1][rt][j] + bv[4 + j], wk);
        }
        BF8 t;
        t.w[0] = pk_bf16(gv[0], gv[1]); t.w[1] = pk_bf16(gv[2], gv[3]);
        t.w[2] = pk_bf16(gv[4], gv[5]); t.w[3] = pk_bf16(gv[6], gv[7]);
        bf16x8 a2 = t.v;
        #pragma unroll
        for (int ct = 0; ct < 4; ++ct)
            acc2[ct][rt] = __builtin_amdgcn_mfma_f32_16x16x32_bf16(a2, Bw[ct], acc2[ct][rt], 0, 0, 0);
    }
}

#define LOADS(A, Bw, bva, bvb, tp) \
    A[0][0] = *(const bf16x8*)(w1p + (((tp) * 32 +  0 + r) << 6) +  0 + g * 8); \
    A[0][1] = *(const bf16x8*)(w1p + (((tp) * 32 +  0 + r) << 6) + 32 + g * 8); \
    A[1][0] = *(const bf16x8*)(w1p + (((tp) * 32 + 16 + r) << 6) +  0 + g * 8); \
    A[1][1] = *(const bf16x8*)(w1p + (((tp) * 32 + 16 + r) << 6) + 32 + g * 8); \
    Bw[0] = *(const bf16x8*)(w2t + (( 0 + r) << 8) + (tp) * 32 + g * 8); \
    Bw[1] = *(const bf16x8*)(w2t + ((16 + r) << 8) + (tp) * 32 + g * 8); \
    Bw[2] = *(const bf16x8*)(w2t + ((32 + r) << 8) + (tp) * 32 + g * 8); \
    Bw[3] = *(const bf16x8*)(w2t + ((48 + r) << 8) + (tp) * 32 + g * 8); \
    bva = *(const ushort4*)(b1e + (tp) * 32 + 4 * g); \
    bvb = *(const ushort4*)(b1e + (tp) * 32 + 16 + 4 * g);

// ---------------- main MoE-MLP: no LDS, no barriers, 2-stage pipelined ----------------
// grid 512 blocks x 256 thr; each wave owns 64 n-rows of one sample b.
__global__ __launch_bounds__(256, 2)
void moe_main(const float* __restrict__ u, const unsigned short* __restrict__ W1P,
              const unsigned short* __restrict__ W2T, const unsigned short* __restrict__ b1P,
              const float* __restrict__ b2, const float4* __restrict__ route,
              float* __restrict__ out) {
    const int tid = threadIdx.x;
    const int wv = tid >> 6, lane = tid & 63;
    const int r = lane & 15, g = lane >> 4;
    const int b = blockIdx.x >> 4;
    const int nslab = ((blockIdx.x & 15) << 2) + wv;
    const int n0 = nslab << 6;                       // 64 rows per wave

    float4 rd = route[b];

    // ---- u B-fragments: ub[rt][ks] = u[n0+rt*16+r][ks*32+g*8 .. +8] as bf16x8
    const float* ubase = u + ((size_t)b * N_ + n0) * C_;
    bf16x8 ub[4][2];
    #pragma unroll
    for (int rt = 0; rt < 4; ++rt) {
        const float* rp = ubase + (rt * 16 + r) * C_;
        #pragma unroll
        for (int ks = 0; ks < 2; ++ks) {
            float4 lo = *(const float4*)(rp + ks * 32 + g * 8);
            float4 hi = *(const float4*)(rp + ks * 32 + g * 8 + 4);
            BF8 t;
            t.w[0] = pk_bf16(lo.x, lo.y); t.w[1] = pk_bf16(lo.z, lo.w);
            t.w[2] = pk_bf16(hi.x, hi.y); t.w[3] = pk_bf16(hi.z, hi.w);
            ub[rt][ks] = t.v;
        }
    }

    f32x4 acc2[4][4];                                // [ct][rt], spans both experts (wk folded in)
    #pragma unroll
    for (int ct = 0; ct < 4; ++ct)
        #pragma unroll
        for (int rt = 0; rt < 4; ++rt)
            #pragma unroll
            for (int q = 0; q < 4; ++q) acc2[ct][rt][q] = 0.f;

    #pragma unroll
    for (int ke = 0; ke < 2; ++ke) {
        const int e = ke ? __float_as_int(rd.w) : __float_as_int(rd.z);
        const float wk = ke ? rd.y : rd.x;
        const unsigned short* w1p = W1P + (e << 14);
        const unsigned short* w2t = W2T + (e << 14);
        const unsigned short* b1e = b1P + (e << 8);

        bf16x8 Aa[2][2], Ba[4]; ushort4 va0, va1;
        bf16x8 Ab[2][2], Bb[4]; ushort4 vb0, vb1;
        LOADS(Aa, Ba, va0, va1, 0)
        #pragma unroll
        for (int tpp = 0; tpp < 4; ++tpp) {
            LOADS(Ab, Bb, vb0, vb1, 2 * tpp + 1)
            comp_tp(Aa, Ba, va0, va1, wk, ub, acc2);
            if (tpp < 3) { LOADS(Aa, Ba, va0, va1, 2 * tpp + 2) }
            comp_tp(Ab, Bb, vb0, vb1, wk, ub, acc2);
        }
    }

    // ---- epilogue: out = u + acc2 + sum_e wk_e*b2_e   (residual re-read: L2/L3-hot)
    const int e0 = __float_as_int(rd.z), e1i = __float_as_int(rd.w);
    float bsum[4];
    #pragma unroll
    for (int ct = 0; ct < 4; ++ct) {
        int c = ct * 16 + r;
        bsum[ct] = rd.x * b2[e0 * C_ + c] + rd.y * b2[e1i * C_ + c];
    }
    float* obase = out + ((size_t)b * N_ + n0) * C_;
    #pragma unroll
    for (int rt = 0; rt < 4; ++rt)
        #pragma unroll
        for (int j = 0; j < 4; ++j) {
            int row = rt * 16 + 4 * g + j;
            #pragma unroll
            for (int ct = 0; ct < 4; ++ct) {
                int c = ct * 16 + r;
                obase[row * C_ + c] = ubase[row * C_ + c] + acc2[ct][rt][j] + bsum[ct];
            }
        }
}

extern "C" void kernel_launch(void* const* d_in, const int* in_sizes, int n_in,
                              void* d_out, int out_size, void* d_ws, size_t ws_size,
                              hipStream_t stream) {
    const float* u  = (const float*)d_in[0];
    const float* W1 = (const float*)d_in[1];
    const float* b1 = (const float*)d_in[2];
    const float* W2 = (const float*)d_in[3];
    const float* b2 = (const float*)d_in[4];
    const float* Wr = (const float*)d_in[5];
    const float* br = (const float*)d_in[6];
    float* out = (float*)d_out;

    char* ws = (char*)d_ws;
    float* pooled        = (float*)ws;                         // 8192 B
    int* counter         = (int*)(ws + 8192);                  // 64 B slot
    float4* route        = (float4*)(ws + 8256);               // 512 B
    unsigned short* b1P  = (unsigned short*)(ws + 8768);       // 4096 B
    unsigned short* W1P  = (unsigned short*)(ws + 16384);      // 256 KB
    unsigned short* W2T  = (unsigned short*)(ws + 16384 + 262144); // 256 KB  (end = 540672)

    hipMemsetAsync(ws, 0, 8256, stream);   // pooled + counter
    prep_pool<<<1041, 256, 0, stream>>>(W1, W2, b1, u, Wr, br, W1P, W2T, b1P, pooled, counter, route);
    moe_main<<<512, 256, 0, stream>>>(u, W1P, W2T, b1P, b2, route, out);
}

// Round 8
// 160.126 us; speedup vs baseline: 1.2218x; 1.0698x over previous
//
#include <hip/hip_runtime.h>
#include <hip/hip_bf16.h>
#include <math.h>

#define B_ 32
#define N_ 4096
#define C_ 64
#define H_ 256
#define P_ 8
#define NPOOL 1024
#define EBLK 66048   // per-expert staged block: W1L 32768 + W2L 32768 + b1L 512

typedef short bf16x8 __attribute__((ext_vector_type(8)));
typedef float f32x4 __attribute__((ext_vector_type(4)));

union BF8 { bf16x8 v; unsigned int w[4]; unsigned short h[8]; };

__device__ __forceinline__ unsigned short f2bf(float f) {
    union { float f; unsigned int u; } v; v.f = f;
    unsigned int r = v.u + 0x7FFFu + ((v.u >> 16) & 1u);
    return (unsigned short)(r >> 16);
}
__device__ __forceinline__ float bf2f(unsigned short h) {
    union { float f; unsigned int u; } v; v.u = ((unsigned int)h) << 16; return v.f;
}
__device__ __forceinline__ unsigned int pk_bf16(float lo, float hi) {
    unsigned int r;
    asm("v_cvt_pk_bf16_f32 %0, %1, %2" : "=v"(r) : "v"(lo), "v"(hi));
    return r;
}
// wk * gelu_tanh(x)
__device__ __forceinline__ float gelu_w(float x, float wk) {
    float x2 = x * x;
    float y2 = x * fmaf(0.10294322f, x2, 2.30220772f);
    float e  = __builtin_amdgcn_exp2f(y2);
    float rc = __builtin_amdgcn_rcpf(e + 1.0f);
    float wx = wk * x;
    return fmaf(-wx, rc, wx);
}
// h-permutation: h = 32*(t>>1) + 8*(d>>2) + 4*(t&1) + (d&3), p = t*16+d
__device__ __forceinline__ int hperm_p(int p) {
    int t = p >> 4, d = p & 15;
    return ((t >> 1) << 5) + ((d >> 2) << 3) + ((t & 1) << 2) + (d & 3);
}
// async global->LDS, 16B per lane; lds dest is wave-uniform base + lane*16
__device__ __forceinline__ void gload16(const void* g, void* l) {
    __builtin_amdgcn_global_load_lds(
        (const __attribute__((address_space(1))) unsigned int*)g,
        (__attribute__((address_space(3))) unsigned int*)l, 16, 0, 0);
}

// ---------------- prep (fragment-major weight blocks) + pool + last-block router --------
// blocks 0..15 (e=bid>>1): m0: W1L frags + b1L; m1: W2L frags
// blocks 16..1039: pool partial sums (atomic) + last block computes router
// Expert block layout (bytes): [0,32768) W1L[fid=tp*4+tt*2+ks][lane][8]
//                              [32768,65536) W2L[fid=tp*4+ct][lane][8]
//                              [65536,66048) b1L[p] (permuted)
__global__ void prep_pool(const float* __restrict__ W1, const float* __restrict__ W2,
                          const float* __restrict__ b1, const float* __restrict__ u,
                          const float* __restrict__ Wr, const float* __restrict__ br,
                          unsigned short* __restrict__ WL, float* __restrict__ pooled,
                          int* __restrict__ counter, float4* __restrict__ route) {
    __shared__ union {
        unsigned short t[256 * 66];                  // W1 stage [h][c], stride 66
        unsigned short s[64 * 258];                  // W2 stage [c][h], stride 258
        struct { float red[4][64]; float lgAll[B_][P_]; } pr;
    } sh;
    __shared__ int isLast;

    const int bid = blockIdx.x, tid = threadIdx.x;

    if (bid < 16) {
        const int e = bid >> 1, m = bid & 1;
        unsigned short* dstW = WL + (size_t)e * (EBLK / 2);
        if (m == 0) {
            // ---- W1: in [c][h] (64x256 f32) -> sh.t[h][c] -> W1L fragment-major
            const float* src = W1 + (e << 14);
            #pragma unroll
            for (int i = 0; i < 16; ++i) {
                int c = i * 4 + (tid >> 6), h4 = (tid & 63) * 4;
                float4 v = *(const float4*)(src + c * 256 + h4);
                sh.t[(h4 + 0) * 66 + c] = f2bf(v.x);
                sh.t[(h4 + 1) * 66 + c] = f2bf(v.y);
                sh.t[(h4 + 2) * 66 + c] = f2bf(v.z);
                sh.t[(h4 + 3) * 66 + c] = f2bf(v.w);
            }
            __syncthreads();
            #pragma unroll
            for (int i = 0; i < 8; ++i) {
                int idx = i * 256 + tid;             // (fid, lane)
                int fid = idx >> 6, ln = idx & 63;
                int tp = fid >> 2, tt = (fid >> 1) & 1, ks = fid & 1;
                int rr = ln & 15, gg = ln >> 4;
                const unsigned short* sp = &sh.t[hperm_p(tp * 32 + tt * 16 + rr) * 66 + ks * 32 + gg * 8];
                BF8 o;
                #pragma unroll
                for (int mm = 0; mm < 8; ++mm) o.h[mm] = sp[mm];
                *(bf16x8*)(dstW + ((fid * 64 + ln) << 3)) = o.v;
            }
            if (tid < 32) {                          // b1L (permuted bias)
                BF8 o;
                #pragma unroll
                for (int mm = 0; mm < 8; ++mm)
                    o.h[mm] = f2bf(b1[(e << 8) + hperm_p(tid * 8 + mm)]);
                *(bf16x8*)(dstW + 32768 + (tid << 3)) = o.v;
            }
        } else {
            // ---- W2: in [h][c] (256x64 f32) -> sh.s[c][h] -> W2L fragment-major
            const float* src = W2 + (e << 14);
            #pragma unroll
            for (int i = 0; i < 16; ++i) {
                int h = i * 16 + (tid >> 4), c4 = (tid & 15) * 4;
                float4 v = *(const float4*)(src + (h << 6) + c4);
                sh.s[(c4 + 0) * 258 + h] = f2bf(v.x);
                sh.s[(c4 + 1) * 258 + h] = f2bf(v.y);
                sh.s[(c4 + 2) * 258 + h] = f2bf(v.z);
                sh.s[(c4 + 3) * 258 + h] = f2bf(v.w);
            }
            __syncthreads();
            #pragma unroll
            for (int i = 0; i < 8; ++i) {
                int idx = i * 256 + tid;             // (fid, lane)
                int fid = idx >> 6, ln = idx & 63;
                int tp = fid >> 2, ct = fid & 3;
                int rr = ln & 15, gg = ln >> 4;
                const unsigned short* sp = &sh.s[(ct * 16 + rr) * 258 + tp * 32 + gg * 8];
                BF8 o;
                #pragma unroll
                for (int mm = 0; mm < 8; ++mm) o.h[mm] = sp[mm];
                *(bf16x8*)(dstW + 16384 + ((fid * 64 + ln) << 3)) = o.v;
            }
        }
        return;
    }
    // ---- pool ----
    int pb = bid - 16;
    int b = pb >> 5, chunk = pb & 31;
    int c = tid & 63, rg = tid >> 6;
    const float* base = u + ((size_t)b * N_ + (size_t)chunk * 128) * C_;
    float s = 0.f;
    #pragma unroll 4
    for (int i = 0; i < 32; ++i) s += base[(i * 4 + rg) * C_ + c];
    sh.pr.red[rg][c] = s;
    __syncthreads();
    if (tid < 64) {
        float t4 = sh.pr.red[0][tid] + sh.pr.red[1][tid] + sh.pr.red[2][tid] + sh.pr.red[3][tid];
        atomicAdd(&pooled[b * C_ + tid], t4);
        __threadfence();
    }
    __syncthreads();
    if (tid == 0) {
        int old = atomicAdd(counter, 1);
        isLast = (old == NPOOL - 1);
    }
    __syncthreads();
    if (!isLast) return;
    __threadfence();
    // ---- router (256 threads = 32 b x 8 p) ----
    {
        int rb = tid >> 3, p = tid & 7;
        const float* pb2 = pooled + rb * C_;
        float sacc = br[p];
        #pragma unroll
        for (int cc = 0; cc < C_; ++cc) {
            float pv = __hip_atomic_load(&pb2[cc], __ATOMIC_RELAXED, __HIP_MEMORY_SCOPE_AGENT);
            sacc += pv * (1.0f / N_) * Wr[cc * P_ + p];
        }
        sh.pr.lgAll[rb][p] = sacc;
    }
    __syncthreads();
    if (tid < B_) {
        float lg[P_];
        #pragma unroll
        for (int p = 0; p < P_; ++p) lg[p] = sh.pr.lgAll[tid][p];
        int i0 = 0;
        #pragma unroll
        for (int p = 1; p < P_; ++p) if (lg[p] > lg[i0]) i0 = p;   // strict >: lowest idx on tie
        int i1 = (i0 == 0) ? 1 : 0;
        #pragma unroll
        for (int p = 0; p < P_; ++p) if (p != i0 && lg[p] > lg[i1]) i1 = p;
        float e1 = __expf(lg[i1] - lg[i0]);
        float w0 = 1.f / (1.f + e1);
        route[tid] = make_float4(w0, e1 * w0, __int_as_float(i0), __int_as_float(i1));
    }
}

// one tp-step: GEMM1 (bias as C-in) -> wk*gelu -> pack -> GEMM2
__device__ __forceinline__ void comp_tp(const bf16x8 (&A)[2][2], const bf16x8 (&Bw)[4],
                                        ushort4 bva, ushort4 bvb, float wk,
                                        const bf16x8 (&ub)[4][2], f32x4 (&acc2)[4][4]) {
    float bv[8];
    bv[0] = bf2f(bva.x); bv[1] = bf2f(bva.y); bv[2] = bf2f(bva.z); bv[3] = bf2f(bva.w);
    bv[4] = bf2f(bvb.x); bv[5] = bf2f(bvb.y); bv[6] = bf2f(bvb.z); bv[7] = bf2f(bvb.w);
    f32x4 c1[2][4];
    #pragma unroll
    for (int tt = 0; tt < 2; ++tt)
        #pragma unroll
        for (int rt = 0; rt < 4; ++rt)
            #pragma unroll
            for (int q = 0; q < 4; ++q) c1[tt][rt][q] = bv[tt * 4 + q];
    #pragma unroll
    for (int ks = 0; ks < 2; ++ks)
        #pragma unroll
        for (int tt = 0; tt < 2; ++tt)
            #pragma unroll
            for (int rt = 0; rt < 4; ++rt)
                c1[tt][rt] = __builtin_amdgcn_mfma_f32_16x16x32_bf16(A[tt][ks], ub[rt][ks], c1[tt][rt], 0, 0, 0);
    #pragma unroll
    for (int rt = 0; rt < 4; ++rt) {
        float gv[8];
        #pragma unroll
        for (int j = 0; j < 4; ++j) {
            gv[j]     = gelu_w(c1[0][rt][j], wk);
            gv[4 + j] = gelu_w(c1[1][rt][j], wk);
        }
        BF8 t;
        t.w[0] = pk_bf16(gv[0], gv[1]); t.w[1] = pk_bf16(gv[2], gv[3]);
        t.w[2] = pk_bf16(gv[4], gv[5]); t.w[3] = pk_bf16(gv[6], gv[7]);
        bf16x8 a2 = t.v;
        #pragma unroll
        for (int ct = 0; ct < 4; ++ct)
            acc2[ct][rt] = __builtin_amdgcn_mfma_f32_16x16x32_bf16(a2, Bw[ct], acc2[ct][rt], 0, 0, 0);
    }
}

// ---------------- main MoE-MLP: LDS-staged fragment-major weights ----------------
// grid 512 blocks x 256 thr (4 waves); each wave owns 64 n-rows of one sample b.
// Per expert: stage 66KB via global_load_lds (linear copy), then 8 tp-steps of
// ds_read_b128 at lane*16 + immediate (conflict-free, zero addr VALU).
__global__ __launch_bounds__(256, 2)
void moe_main(const float* __restrict__ u, const unsigned short* __restrict__ WL,
              const float* __restrict__ b2, const float4* __restrict__ route,
              float* __restrict__ out) {
    __shared__ __align__(16) unsigned char wlds[EBLK];

    const int tid = threadIdx.x;
    const int wv = tid >> 6, lane = tid & 63;
    const int r = lane & 15, g = lane >> 4;
    const int lbyte = lane * 16;
    const int b = blockIdx.x >> 4;
    const int n0 = (((blockIdx.x & 15) << 2) + wv) << 6;   // 64 rows per wave

    float4 rd = route[b];

    // ---- u B-fragments: ub[rt][ks] = u[n0+rt*16+r][ks*32+g*8 .. +8] as bf16x8
    const float* ubase = u + ((size_t)b * N_ + n0) * C_;
    bf16x8 ub[4][2];
    #pragma unroll
    for (int rt = 0; rt < 4; ++rt) {
        const float* rp = ubase + (rt * 16 + r) * C_;
        #pragma unroll
        for (int ks = 0; ks < 2; ++ks) {
            float4 lo = *(const float4*)(rp + ks * 32 + g * 8);
            float4 hi = *(const float4*)(rp + ks * 32 + g * 8 + 4);
            BF8 t;
            t.w[0] = pk_bf16(lo.x, lo.y); t.w[1] = pk_bf16(lo.z, lo.w);
            t.w[2] = pk_bf16(hi.x, hi.y); t.w[3] = pk_bf16(hi.z, hi.w);
            ub[rt][ks] = t.v;
        }
    }

    f32x4 acc2[4][4];                                // [ct][rt], spans both experts (wk folded in)
    #pragma unroll
    for (int ct = 0; ct < 4; ++ct)
        #pragma unroll
        for (int rt = 0; rt < 4; ++rt)
            #pragma unroll
            for (int q = 0; q < 4; ++q) acc2[ct][rt][q] = 0.f;

    for (int ke = 0; ke < 2; ++ke) {
        const int e = ke ? __float_as_int(rd.w) : __float_as_int(rd.z);
        const float wk = ke ? rd.y : rd.x;

        if (ke) __syncthreads();                     // all waves done reading prev expert
        // ---- stage expert block: pure linear 66KB copy, 16B/lane async
        const char* wsrc = (const char*)WL + (size_t)e * EBLK;
        #pragma unroll
        for (int i2 = 0; i2 < 16; ++i2)
            gload16(wsrc + i2 * 4096 + wv * 1024 + lbyte, &wlds[i2 * 4096 + wv * 1024]);
        if (tid < 32)
            gload16(wsrc + 65536 + lbyte, &wlds[65536]);
        __syncthreads();                             // compiler drains vmcnt before barrier

        #pragma unroll
        for (int tp = 0; tp < 8; ++tp) {
            bf16x8 A[2][2], Bw[4];
            #pragma unroll
            for (int tt = 0; tt < 2; ++tt)
                #pragma unroll
                for (int ks = 0; ks < 2; ++ks)
                    A[tt][ks] = *(const bf16x8*)&wlds[((tp * 4 + tt * 2 + ks) << 10) + lbyte];
            #pragma unroll
            for (int ct = 0; ct < 4; ++ct)
                Bw[ct] = *(const bf16x8*)&wlds[32768 + ((tp * 4 + ct) << 10) + lbyte];
            ushort4 bva = *(const ushort4*)&wlds[65536 + tp * 64 + g * 8];
            ushort4 bvb = *(const ushort4*)&wlds[65536 + tp * 64 + 32 + g * 8];
            comp_tp(A, Bw, bva, bvb, wk, ub, acc2);
        }
    }

    // ---- epilogue: out = u + acc2 + sum_e wk_e*b2_e   (residual re-read: L2/L3-hot)
    const int e0 = __float_as_int(rd.z), e1i = __float_as_int(rd.w);
    float bsum[4];
    #pragma unroll
    for (int ct = 0; ct < 4; ++ct) {
        int c = ct * 16 + r;
        bsum[ct] = rd.x * b2[e0 * C_ + c] + rd.y * b2[e1i * C_ + c];
    }
    float* obase = out + ((size_t)b * N_ + n0) * C_;
    #pragma unroll
    for (int rt = 0; rt < 4; ++rt)
        #pragma unroll
        for (int j = 0; j < 4; ++j) {
            int row = rt * 16 + 4 * g + j;
            #pragma unroll
            for (int ct = 0; ct < 4; ++ct) {
                int c = ct * 16 + r;
                obase[row * C_ + c] = ubase[row * C_ + c] + acc2[ct][rt][j] + bsum[ct];
            }
        }
}

extern "C" void kernel_launch(void* const* d_in, const int* in_sizes, int n_in,
                              void* d_out, int out_size, void* d_ws, size_t ws_size,
                              hipStream_t stream) {
    const float* u  = (const float*)d_in[0];
    const float* W1 = (const float*)d_in[1];
    const float* b1 = (const float*)d_in[2];
    const float* W2 = (const float*)d_in[3];
    const float* b2 = (const float*)d_in[4];
    const float* Wr = (const float*)d_in[5];
    const float* br = (const float*)d_in[6];
    float* out = (float*)d_out;

    char* ws = (char*)d_ws;
    float* pooled       = (float*)ws;                          // 8192 B
    int* counter        = (int*)(ws + 8192);                   // 64 B slot
    float4* route       = (float4*)(ws + 8256);                // 512 B
    unsigned short* WL  = (unsigned short*)(ws + 16384);       // 8 x 66048 B = 528384 (end 544768)

    hipMemsetAsync(ws, 0, 8256, stream);   // pooled + counter
    prep_pool<<<1040, 256, 0, stream>>>(W1, W2, b1, u, Wr, br, WL, pooled, counter, route);
    moe_main<<<512, 256, 0, stream>>>(u, WL, b2, route, out);
}